// Round 1
// baseline (120920.886 us; speedup 1.0000x reference)
//
#include <hip/hip_runtime.h>

// NODE scan: 32 groups x 8 blocks; group = 16 batch rows; block owns a
// 64-col slice of W1/W2, 16 cols of W3, 8 cols of Wr (LDS-resident, f16).
// Per step: A(z@W1) -> flag/broadcast a1 -> B(a1@W2) -> flag/broadcast a2
// -> C(a2@W3 -> v) -> flag/broadcast v -> D(h+=0.1v, build z, latents).
// out_t = h_t @ Wr computed one step late in the flag1 wait gap (+ epilogue).

#define TT 1000
#define II 16
#define LL 128
#define HH 512
#define OO 64
#define BB 512
#define BR 16
#define CHUNK 64

typedef _Float16 f16;
typedef _Float16 f16x8 __attribute__((ext_vector_type(8)));
typedef _Float16 f16x4 __attribute__((ext_vector_type(4)));
typedef float    f32x4 __attribute__((ext_vector_type(4)));

#define MFMA16(a, b, c) __builtin_amdgcn_mfma_f32_16x16x32_f16((a), (b), (c), 0, 0, 0)

// LDS strides (f16 elems): K padded so row-stride(dwords) % 32 == 4 or 20
// -> 16 MFMA-frag rows spread over 8 banks (2-way conflict = free).
#define ZS  520   // a1/a2/z staging buffer stride (K=512 / K=160 for z)
#define W1S 168   // K=160 (144 zero-padded)
#define W3S 520
#define WRS 136   // K=128

struct Lds {
  f16 w1t[64][W1S];   // W1^T slice: [n=64 cols of this block][k=160]
  f16 w2t[64][ZS];    // W2^T slice
  f16 w3t[16][W3S];   // W3^T slice (16 v-cols)
  f16 wrt[16][WRS];   // Wr^T slice (8 real out-cols + 8 zero)
  f16 act[16][ZS];    // phase A: z=[h|x|0]; phase B: a1; phase C: a2
  float h[16][LL];    // fp32 running state (replicated per block)
  float b1c[64], b2c[64], b3c[16], brc[16];
};

__device__ __forceinline__ void grp_release(unsigned* f, unsigned val, int tid) {
  __threadfence();            // drain + make stores agent-visible
  __syncthreads();
  if (tid == 0)
    __hip_atomic_store(f, val, __ATOMIC_RELEASE, __HIP_MEMORY_SCOPE_AGENT);
}

__device__ __forceinline__ void grp_wait(unsigned* f, unsigned tgt, int tid) {
  if (tid >= 64 && tid < 72) {  // wave1 lanes 0..7: one coalesced poll load
    while (__hip_atomic_load(&f[tid - 64], __ATOMIC_RELAXED,
                             __HIP_MEMORY_SCOPE_AGENT) < tgt) { }
  }
  __syncthreads();
  __threadfence();            // acquire: invalidate caches before data reads
}

__launch_bounds__(256, 1)
__global__ void node_scan_kernel(
    const float* __restrict__ x,
    const float* __restrict__ W1, const float* __restrict__ b1,
    const float* __restrict__ W2, const float* __restrict__ b2,
    const float* __restrict__ W3, const float* __restrict__ b3,
    const float* __restrict__ Wr, const float* __restrict__ br,
    float* __restrict__ out,
    unsigned* __restrict__ flags,
    f16* __restrict__ a1buf, f16* __restrict__ a2buf,
    float* __restrict__ vbuf)
{
  __shared__ Lds s;
  const int tid  = threadIdx.x;
  const int bid  = blockIdx.x;
  // group decomposition: 8 members of a group share bid%8 -> same XCD (heuristic)
  const int xcd  = bid & 7;
  const int q    = bid >> 3;
  const int j    = q & 7;               // member 0..7
  const int g    = xcd + 8 * (q >> 3);  // group 0..31
  const int r0   = g * BR;              // batch row base
  const int lane = tid & 63;
  const int w    = tid >> 6;            // wave 0..3
  const int lr   = lane & 15;
  const int lk   = lane >> 4;

  float* lat = out + (size_t)BB * TT * OO;

  // ---------------- prologue: weights -> LDS (transposed, f16) ------------
  { int n = tid & 63, ks = tid >> 6;
    for (int k = ks; k < 144; k += 4)      s.w1t[n][k] = (f16)W1[(size_t)k * HH + CHUNK * j + n];
    for (int k = 144 + ks; k < W1S; k += 4) s.w1t[n][k] = (f16)0.f;
    for (int k = ks; k < HH; k += 4)       s.w2t[n][k] = (f16)W2[(size_t)k * HH + CHUNK * j + n];
  }
  { int n = tid & 15, ks = tid >> 4;
    for (int k = ks; k < HH; k += 16) s.w3t[n][k] = (f16)W3[(size_t)k * LL + 16 * j + n];
    for (int k = ks; k < LL; k += 16) s.wrt[n][k] = (n < 8) ? (f16)Wr[(size_t)k * OO + 8 * j + n] : (f16)0.f;
  }
  if (tid < 64)      { s.b1c[tid] = b1[CHUNK * j + tid]; s.b2c[tid] = b2[CHUNK * j + tid]; }
  else if (tid < 80) { s.b3c[tid - 64] = b3[16 * j + (tid - 64)]; }
  else if (tid < 96) { int n = tid - 80; s.brc[n] = (n < 8) ? br[8 * j + n] : 0.f; }
  for (int i = tid; i < 16 * LL; i += 256) s.h[i >> 7][i & (LL - 1)] = 0.f;
  for (int i = tid; i < 16 * ZS; i += 256) s.act[i / ZS][i % ZS] = (f16)0.f;
  __syncthreads();
  const size_t xoff = (size_t)(r0 + (tid >> 4)) * TT * II + (tid & 15);
  s.act[tid >> 4][128 + (tid & 15)] = (f16)x[xoff];   // z_0 = [0 | x_0 | 0]
  __syncthreads();

  unsigned* const fl = flags + g * 32;   // [stage 0..2][member 0..7], 128B/group
  float xreg = 0.f;

  for (int t = 0; t < TT; ++t) {
    const int par = t & 1;
    const size_t abase = ((size_t)(g * 2 + par) * 16) * 512;   // a1/a2 buf elem base
    const size_t vbase = ((size_t)(g * 2 + par) * 16) * 128;

    // ---------------- phase A: a1_chunk = relu(z @ W1_slice + b1) ----------
    {
      const int bn = w * 16 + lr;
      f32x4 c = {0.f, 0.f, 0.f, 0.f};
#pragma unroll
      for (int kt = 0; kt < 5; ++kt) {
        f16x8 a  = *(const f16x8*)&s.act[lr][kt * 32 + lk * 8];
        f16x8 bf = *(const f16x8*)&s.w1t[bn][kt * 32 + lk * 8];
        c = MFMA16(a, bf, c);
      }
      f16* dst = a1buf + abase + CHUNK * j + bn;
      const float bv = s.b1c[bn];
#pragma unroll
      for (int e = 0; e < 4; ++e) {
        float vv = c[e] + bv; vv = vv > 0.f ? vv : 0.f;
        dst[(size_t)(lk * 4 + e) * 512] = (f16)vv;
      }
    }
    grp_release(&fl[0 + j], (unsigned)(t + 1), tid);

    // gap work while waiting for a1 broadcast:
    if (t + 1 < TT) xreg = x[xoff + (size_t)(t + 1) * II];   // prefetch x_{t+1}
    if (w == 0 && t >= 1) {  // out_{t-1} = h_{t-1} @ Wr + br  (z holds h_{t-1})
      f32x4 c = {0.f, 0.f, 0.f, 0.f};
#pragma unroll
      for (int kt = 0; kt < 4; ++kt) {
        f16x8 a  = *(const f16x8*)&s.act[lr][kt * 32 + lk * 8];
        f16x8 bf = *(const f16x8*)&s.wrt[lr][kt * 32 + lk * 8];
        c = MFMA16(a, bf, c);
      }
      if (lr < 8) {
        const float bv = s.brc[lr];
#pragma unroll
        for (int e = 0; e < 4; ++e)
          out[((size_t)(r0 + lk * 4 + e) * TT + (t - 1)) * OO + 8 * j + lr] = c[e] + bv;
      }
    }
    grp_wait(&fl[0], (unsigned)(t + 1), tid);

    // stage full a1 [16,512] f16 -> act
    {
      const uint4* src = (const uint4*)(a1buf + abase);
#pragma unroll
      for (int it = 0; it < 4; ++it) {
        int qd = tid + it * 256;               // 1024 x 16B
        int r = qd >> 6, c8 = (qd & 63) * 8;
        *(uint4*)&s.act[r][c8] = src[qd];
      }
    }
    __syncthreads();

    // ---------------- phase B: a2_chunk = relu(a1 @ W2_slice + b2) ---------
    {
      const int bn = w * 16 + lr;
      f32x4 c = {0.f, 0.f, 0.f, 0.f};
#pragma unroll
      for (int kt = 0; kt < 16; ++kt) {
        f16x8 a  = *(const f16x8*)&s.act[lr][kt * 32 + lk * 8];
        f16x8 bf = *(const f16x8*)&s.w2t[bn][kt * 32 + lk * 8];
        c = MFMA16(a, bf, c);
      }
      f16* dst = a2buf + abase + CHUNK * j + bn;
      const float bv = s.b2c[bn];
#pragma unroll
      for (int e = 0; e < 4; ++e) {
        float vv = c[e] + bv; vv = vv > 0.f ? vv : 0.f;
        dst[(size_t)(lk * 4 + e) * 512] = (f16)vv;
      }
    }
    grp_release(&fl[8 + j], (unsigned)(t + 1), tid);
    grp_wait(&fl[8], (unsigned)(t + 1), tid);

    // stage full a2 -> act
    {
      const uint4* src = (const uint4*)(a2buf + abase);
#pragma unroll
      for (int it = 0; it < 4; ++it) {
        int qd = tid + it * 256;
        int r = qd >> 6, c8 = (qd & 63) * 8;
        *(uint4*)&s.act[r][c8] = src[qd];
      }
    }
    __syncthreads();

    // ---------------- phase C: v_chunk = a2 @ W3_slice + b3 (wave0) --------
    if (w == 0) {
      f32x4 c = {0.f, 0.f, 0.f, 0.f};
#pragma unroll
      for (int kt = 0; kt < 16; ++kt) {
        f16x8 a  = *(const f16x8*)&s.act[lr][kt * 32 + lk * 8];
        f16x8 bf = *(const f16x8*)&s.w3t[lr][kt * 32 + lk * 8];
        c = MFMA16(a, bf, c);
      }
      float* dst = vbuf + vbase + 16 * j + lr;
      const float bv = s.b3c[lr];
#pragma unroll
      for (int e = 0; e < 4; ++e)
        dst[(size_t)(lk * 4 + e) * 128] = c[e] + bv;
    }
    grp_release(&fl[16 + j], (unsigned)(t + 1), tid);
    grp_wait(&fl[16], (unsigned)(t + 1), tid);

    // ---------------- phase D: h += 0.1 v; rebuild z; write latents --------
    {
      const float4* vsrc = (const float4*)(vbuf + vbase);
#pragma unroll
      for (int it = 0; it < 2; ++it) {
        int idx = tid + it * 256;              // 512 x float4
        int r = idx >> 5, c4 = (idx & 31) * 4;
        float4 vv = vsrc[idx];
        float h0 = s.h[r][c4 + 0] + 0.1f * vv.x;
        float h1 = s.h[r][c4 + 1] + 0.1f * vv.y;
        float h2 = s.h[r][c4 + 2] + 0.1f * vv.z;
        float h3 = s.h[r][c4 + 3] + 0.1f * vv.w;
        s.h[r][c4 + 0] = h0; s.h[r][c4 + 1] = h1;
        s.h[r][c4 + 2] = h2; s.h[r][c4 + 3] = h3;
        f16x4 zf = {(f16)h0, (f16)h1, (f16)h2, (f16)h3};
        *(f16x4*)&s.act[r][c4] = zf;
      }
      int r = tid >> 4, cc = tid & 15;
      s.act[r][128 + cc] = (t + 1 < TT) ? (f16)xreg : (f16)0.f;
      s.act[r][144 + cc] = (f16)0.f;           // re-zero K pad (staging clobbered it)
    }
    __syncthreads();
    {
      int r = tid >> 4, cc = tid & 15;
      lat[((size_t)(r0 + r) * TT + t) * LL + 16 * j + cc] = s.h[r][16 * j + cc];
    }
  }

  // epilogue: out_{T-1} = h_{T-1} @ Wr + br (z holds h_{T-1})
  if (w == 0) {
    f32x4 c = {0.f, 0.f, 0.f, 0.f};
#pragma unroll
    for (int kt = 0; kt < 4; ++kt) {
      f16x8 a  = *(const f16x8*)&s.act[lr][kt * 32 + lk * 8];
      f16x8 bf = *(const f16x8*)&s.wrt[lr][kt * 32 + lk * 8];
      c = MFMA16(a, bf, c);
    }
    if (lr < 8) {
      const float bv = s.brc[lr];
#pragma unroll
      for (int e = 0; e < 4; ++e)
        out[((size_t)(r0 + lk * 4 + e) * TT + (TT - 1)) * OO + 8 * j + lr] = c[e] + bv;
    }
  }
}

extern "C" void kernel_launch(void* const* d_in, const int* in_sizes, int n_in,
                              void* d_out, int out_size, void* d_ws, size_t ws_size,
                              hipStream_t stream) {
  const float* x  = (const float*)d_in[0];
  const float* W1 = (const float*)d_in[1];
  const float* b1 = (const float*)d_in[2];
  const float* W2 = (const float*)d_in[3];
  const float* b2 = (const float*)d_in[4];
  const float* W3 = (const float*)d_in[5];
  const float* b3 = (const float*)d_in[6];
  const float* Wr = (const float*)d_in[7];
  const float* br = (const float*)d_in[8];
  float* out = (float*)d_out;

  // ws layout: [0,4K) flags | 1MB a1buf f16 | 1MB a2buf f16 | 512KB vbuf f32
  unsigned* flags = (unsigned*)d_ws;
  f16*   a1buf = (f16*)((char*)d_ws + 4096);
  f16*   a2buf = (f16*)((char*)d_ws + 4096 + (1 << 20));
  float* vbuf  = (float*)((char*)d_ws + 4096 + (2 << 20));

  hipMemsetAsync(d_ws, 0, 4096, stream);   // reset flags every launch/replay
  node_scan_kernel<<<256, 256, 0, stream>>>(x, W1, b1, W2, b2, W3, b3, Wr, br,
                                            out, flags, a1buf, a2buf, vbuf);
}

// Round 2
// 6760.323 us; speedup vs baseline: 17.8869x; 17.8869x over previous
//
#include <hip/hip_runtime.h>

// NODE scan, 2-sync/step: 32 groups x 8 blocks; group = 16 batch rows.
// Block j owns 64-col slice of W1/W2, 64-ROW slice of W3 (-> partial v),
// 8 cols of Wr. All cross-block traffic via write-through (sc0 sc1) loads/
// stores coherent at L3 -- NO threadfence / buffer_wbl2 / buffer_inv.
// Per step: A(z@W1 chunk) -> flag/bcast a1 -> B(a1@W2 chunk) ->
// C'(a2_chunk@W3_rows -> partial v) -> flag/bcast vp -> D(reduce 8 partials,
// h += 0.1 v, rebuild z, latents).  out_t = h_t @ Wr done in the sync1 gap.

#define TT 1000
#define II 16
#define LL 128
#define HH 512
#define OO 64
#define BB 512
#define BR 16

typedef _Float16 f16;
typedef _Float16 f16x8 __attribute__((ext_vector_type(8)));
typedef _Float16 f16x4 __attribute__((ext_vector_type(4)));
typedef float    f32x4 __attribute__((ext_vector_type(4)));
typedef unsigned u32x4 __attribute__((ext_vector_type(4)));

#define MFMA16(a, b, c) __builtin_amdgcn_mfma_f32_16x16x32_f16((a), (b), (c), 0, 0, 0)

// LDS K-strides (f16): dword-stride % 32 == 4 or 20 -> frag rows spread banks
#define ZS  520   // act: z (K=160) / a1 (K=512) / a2-chunk (K=64)
#define W1S 168   // K=160 (144 + zero pad)
#define W3S 72    // K=64 (row-slice of W3)
#define WRS 136   // K=128

struct Lds {
  f16 w1t[64][W1S];    // W1^T col-slice: [n=64][k=160]
  f16 w2t[64][ZS];     // W2^T col-slice: [n=64][k=512]
  f16 w3t[128][W3S];   // W3^T row-slice: [n=128][k=64 local]
  f16 wrt[16][WRS];    // Wr^T slice (8 real cols + 8 zero)
  f16 act[16][ZS];     // z / a1 / a2-chunk staging
  float h[16][LL];     // fp32 running state (replicated per block)
  float b1c[64], b2c[64], b3c[128], brc[16];
};

// ---- write-through (coherent-at-L3) primitives: no cache maintenance ----
__device__ __forceinline__ void st_thru_u32(void* p, unsigned v) {
  asm volatile("global_store_dword %0, %1, off sc0 sc1" :: "v"(p), "v"(v) : "memory");
}
__device__ __forceinline__ void st_thru_sh(void* p, unsigned v) {
  asm volatile("global_store_short %0, %1, off sc0 sc1" :: "v"(p), "v"(v) : "memory");
}
__device__ __forceinline__ u32x4 ld_thru_u4(const void* p) {
  u32x4 r;
  asm volatile("global_load_dwordx4 %0, %1, off sc0 sc1" : "=v"(r) : "v"(p) : "memory");
  return r;
}
__device__ __forceinline__ unsigned ld_thru_u32(const void* p) {
  unsigned r;
  asm volatile("global_load_dword %0, %1, off sc0 sc1\n\ts_waitcnt vmcnt(0)"
               : "=v"(r) : "v"(p) : "memory");
  return r;
}
__device__ __forceinline__ void vm_drain() {
  asm volatile("s_waitcnt vmcnt(0)" ::: "memory");
  __builtin_amdgcn_sched_barrier(0);   // rule #18: pin uses after the wait
}

// producer: per-wave drain of its own thru-stores, then one flag store
__device__ __forceinline__ void grp_release(unsigned* f, unsigned val, int tid) {
  vm_drain();
  __syncthreads();
  if (tid == 0) st_thru_u32(f, val);
}
// consumer: 8 lanes of wave1 poll the 8 member flags at L3
__device__ __forceinline__ void grp_wait(unsigned* f, unsigned tgt, int tid) {
  if (tid >= 64 && tid < 72) {
    const unsigned* fp = f + (tid - 64);
    while (ld_thru_u32(fp) < tgt) { }
  }
  __syncthreads();
}

__launch_bounds__(256, 1)
__global__ void node_scan_kernel(
    const float* __restrict__ x,
    const float* __restrict__ W1, const float* __restrict__ b1,
    const float* __restrict__ W2, const float* __restrict__ b2,
    const float* __restrict__ W3, const float* __restrict__ b3,
    const float* __restrict__ Wr, const float* __restrict__ br,
    float* __restrict__ out,
    unsigned* __restrict__ flags,
    f16* __restrict__ a1buf, f16* __restrict__ vpbuf)
{
  __shared__ Lds s;
  const int tid  = threadIdx.x;
  const int bid  = blockIdx.x;
  const int xcd  = bid & 7;             // 8 members of a group share an XCD
  const int q    = bid >> 3;
  const int j    = q & 7;               // member 0..7
  const int g    = xcd + 8 * (q >> 3);  // group 0..31
  const int r0   = g * BR;
  const int lane = tid & 63;
  const int w    = tid >> 6;
  const int lr   = lane & 15;
  const int lk   = lane >> 4;

  float* lat = out + (size_t)BB * TT * OO;

  // ---------------- prologue: weights -> LDS (transposed, f16) ------------
  { int n = tid & 63, ks = tid >> 6;
    for (int k = ks; k < 144; k += 4)       s.w1t[n][k] = (f16)W1[(size_t)k * HH + 64 * j + n];
    for (int k = 144 + ks; k < W1S; k += 4) s.w1t[n][k] = (f16)0.f;
    for (int k = ks; k < HH; k += 4)        s.w2t[n][k] = (f16)W2[(size_t)k * HH + 64 * j + n];
  }
  for (int idx = tid; idx < 128 * 64; idx += 256) {   // W3 rows 64j..64j+63
    int kl = idx >> 7, n = idx & 127;
    s.w3t[n][kl] = (f16)W3[(size_t)(64 * j + kl) * LL + n];
  }
  { int n = tid & 15, ks = tid >> 4;
    for (int k = ks; k < LL; k += 16)
      s.wrt[n][k] = (n < 8) ? (f16)Wr[(size_t)k * OO + 8 * j + n] : (f16)0.f;
  }
  if (tid < 64)       { s.b1c[tid] = b1[64 * j + tid]; s.b2c[tid] = b2[64 * j + tid]; }
  else if (tid < 192) { s.b3c[tid - 64] = b3[tid - 64]; }
  else if (tid < 208) { int n = tid - 192; s.brc[n] = (n < 8) ? br[8 * j + n] : 0.f; }
  for (int i = tid; i < 16 * LL; i += 256) s.h[i >> 7][i & (LL - 1)] = 0.f;
  for (int i = tid; i < 16 * ZS; i += 256) s.act[i / ZS][i % ZS] = (f16)0.f;
  __syncthreads();
  const size_t xoff = (size_t)(r0 + (tid >> 4)) * TT * II + (tid & 15);
  s.act[tid >> 4][128 + (tid & 15)] = (f16)x[xoff];   // z_0 = [0 | x_0 | 0]
  __syncthreads();

  unsigned* const fl = flags + g * 32;
  float xreg = 0.f;

  for (int t = 0; t < TT; ++t) {
    const int par = t & 1;
    f16* const a1b = a1buf + ((size_t)(g * 2 + par)) * (16 * 512);
    f16* const vpb = vpbuf + ((size_t)(g * 2 + par)) * (8 * 2048);

    // -------- phase A: a1_chunk = relu(z @ W1_slice + b1), thru-store -----
    {
      const int bn = w * 16 + lr;
      f32x4 c = {0.f, 0.f, 0.f, 0.f};
#pragma unroll
      for (int kt = 0; kt < 5; ++kt) {
        f16x8 a  = *(const f16x8*)&s.act[lr][kt * 32 + lk * 8];
        f16x8 bf = *(const f16x8*)&s.w1t[bn][kt * 32 + lk * 8];
        c = MFMA16(a, bf, c);
      }
      f16* dst = a1b + 64 * j + bn;
      const float bv = s.b1c[bn];
#pragma unroll
      for (int e = 0; e < 4; ++e) {
        float vv = c[e] + bv; vv = vv > 0.f ? vv : 0.f;
        unsigned short us = __builtin_bit_cast(unsigned short, (f16)vv);
        st_thru_sh(dst + (size_t)(lk * 4 + e) * 512, (unsigned)us);
      }
    }
    grp_release(&fl[0 + j], (unsigned)(t + 1), tid);

    // gap: prefetch x_{t+1}; out_{t-1} = h_{t-1} @ Wr + br (act holds z_{t-1})
    if (t + 1 < TT) xreg = x[xoff + (size_t)(t + 1) * II];
    if (w == 0 && t >= 1) {
      f32x4 c = {0.f, 0.f, 0.f, 0.f};
#pragma unroll
      for (int kt = 0; kt < 4; ++kt) {
        f16x8 a  = *(const f16x8*)&s.act[lr][kt * 32 + lk * 8];
        f16x8 bf = *(const f16x8*)&s.wrt[lr][kt * 32 + lk * 8];
        c = MFMA16(a, bf, c);
      }
      if (lr < 8) {
        const float bv = s.brc[lr];
#pragma unroll
        for (int e = 0; e < 4; ++e)
          out[((size_t)(r0 + lk * 4 + e) * TT + (t - 1)) * OO + 8 * j + lr] = c[e] + bv;
      }
    }
    grp_wait(&fl[0], (unsigned)(t + 1), tid);

    // stage full a1 [16,512] f16 from L3 -> act
    {
      u32x4 t0 = ld_thru_u4(a1b + (size_t)(tid +   0) * 8);
      u32x4 t1 = ld_thru_u4(a1b + (size_t)(tid + 256) * 8);
      u32x4 t2 = ld_thru_u4(a1b + (size_t)(tid + 512) * 8);
      u32x4 t3 = ld_thru_u4(a1b + (size_t)(tid + 768) * 8);
      vm_drain();
      *(u32x4*)&s.act[(tid +   0) >> 6][((tid +   0) & 63) * 8] = t0;
      *(u32x4*)&s.act[(tid + 256) >> 6][((tid + 256) & 63) * 8] = t1;
      *(u32x4*)&s.act[(tid + 512) >> 6][((tid + 512) & 63) * 8] = t2;
      *(u32x4*)&s.act[(tid + 768) >> 6][((tid + 768) & 63) * 8] = t3;
    }
    __syncthreads();

    // -------- phase B: a2_chunk = relu(a1 @ W2_slice + b2) (regs) ---------
    f32x4 cb;
    {
      const int bn = w * 16 + lr;
      f32x4 c0 = {0.f, 0.f, 0.f, 0.f}, c1 = {0.f, 0.f, 0.f, 0.f};
#pragma unroll
      for (int kt = 0; kt < 16; kt += 2) {
        f16x8 a0 = *(const f16x8*)&s.act[lr][kt * 32 + lk * 8];
        f16x8 b0 = *(const f16x8*)&s.w2t[bn][kt * 32 + lk * 8];
        c0 = MFMA16(a0, b0, c0);
        f16x8 a1_ = *(const f16x8*)&s.act[lr][(kt + 1) * 32 + lk * 8];
        f16x8 b1_ = *(const f16x8*)&s.w2t[bn][(kt + 1) * 32 + lk * 8];
        c1 = MFMA16(a1_, b1_, c1);
      }
      const float bv = s.b2c[bn];
#pragma unroll
      for (int e = 0; e < 4; ++e) {
        float vv = c0[e] + c1[e] + bv;
        cb[e] = vv > 0.f ? vv : 0.f;
      }
    }
    __syncthreads();               // all waves done reading a1 in act
    {                              // write a2_chunk [16 x 64] into act k=0..63
      const int bn = w * 16 + lr;
#pragma unroll
      for (int e = 0; e < 4; ++e)
        s.act[lk * 4 + e][bn] = (f16)cb[e];
    }
    __syncthreads();

    // -------- phase C': vp = a2_chunk @ W3_rows (partial v, f16 out) ------
    {
      const int nt0 = 2 * w, nt1 = 2 * w + 1;
      f32x4 c0 = {0.f, 0.f, 0.f, 0.f}, c1 = {0.f, 0.f, 0.f, 0.f};
#pragma unroll
      for (int kt = 0; kt < 2; ++kt) {
        f16x8 a  = *(const f16x8*)&s.act[lr][kt * 32 + lk * 8];
        f16x8 b0 = *(const f16x8*)&s.w3t[nt0 * 16 + lr][kt * 32 + lk * 8];
        c0 = MFMA16(a, b0, c0);
        f16x8 b1_ = *(const f16x8*)&s.w3t[nt1 * 16 + lr][kt * 32 + lk * 8];
        c1 = MFMA16(a, b1_, c1);
      }
      f16* dst = vpb + (size_t)j * 2048;
#pragma unroll
      for (int e = 0; e < 4; ++e) {
        unsigned short u0 = __builtin_bit_cast(unsigned short, (f16)c0[e]);
        unsigned short u1 = __builtin_bit_cast(unsigned short, (f16)c1[e]);
        st_thru_sh(dst + (size_t)(lk * 4 + e) * 128 + nt0 * 16 + lr, (unsigned)u0);
        st_thru_sh(dst + (size_t)(lk * 4 + e) * 128 + nt1 * 16 + lr, (unsigned)u1);
      }
    }
    grp_release(&fl[8 + j], (unsigned)(t + 1), tid);
    grp_wait(&fl[8], (unsigned)(t + 1), tid);

    // -------- phase D: v = sum_j vp_j + b3; h += 0.1 v; rebuild z ---------
    {
      const int r = tid >> 4, c8 = (tid & 15) * 8;   // 16 rows x 128 cols
      const f16* vb = vpb + (size_t)r * 128 + c8;
      u32x4 p[8];
#pragma unroll
      for (int m = 0; m < 8; ++m) p[m] = ld_thru_u4(vb + (size_t)m * 2048);
      vm_drain();
      float sum[8] = {0.f, 0.f, 0.f, 0.f, 0.f, 0.f, 0.f, 0.f};
#pragma unroll
      for (int m = 0; m < 8; ++m) {
        f16x8 ph = __builtin_bit_cast(f16x8, p[m]);
#pragma unroll
        for (int e = 0; e < 8; ++e) sum[e] += (float)ph[e];
      }
      f16x8 zf;
#pragma unroll
      for (int e = 0; e < 8; ++e) {
        float hv = s.h[r][c8 + e] + 0.1f * (sum[e] + s.b3c[c8 + e]);
        s.h[r][c8 + e] = hv;
        zf[e] = (f16)hv;
      }
      *(f16x8*)&s.act[r][c8] = zf;
      const int cc = tid & 15;
      s.act[r][128 + cc] = (t + 1 < TT) ? (f16)xreg : (f16)0.f;
      s.act[r][144 + cc] = (f16)0.f;   // K pad (staging clobbered it)
    }
    __syncthreads();
    {
      int r = tid >> 4, cc = tid & 15;
      lat[((size_t)(r0 + r) * TT + t) * LL + 16 * j + cc] = s.h[r][16 * j + cc];
    }
  }

  // epilogue: out_{T-1} = h_{T-1} @ Wr + br (act holds z_{T-1})
  if (w == 0) {
    f32x4 c = {0.f, 0.f, 0.f, 0.f};
#pragma unroll
    for (int kt = 0; kt < 4; ++kt) {
      f16x8 a  = *(const f16x8*)&s.act[lr][kt * 32 + lk * 8];
      f16x8 bf = *(const f16x8*)&s.wrt[lr][kt * 32 + lk * 8];
      c = MFMA16(a, bf, c);
    }
    if (lr < 8) {
      const float bv = s.brc[lr];
#pragma unroll
      for (int e = 0; e < 4; ++e)
        out[((size_t)(r0 + lk * 4 + e) * TT + (TT - 1)) * OO + 8 * j + lr] = c[e] + bv;
    }
  }
}

extern "C" void kernel_launch(void* const* d_in, const int* in_sizes, int n_in,
                              void* d_out, int out_size, void* d_ws, size_t ws_size,
                              hipStream_t stream) {
  const float* x  = (const float*)d_in[0];
  const float* W1 = (const float*)d_in[1];
  const float* b1 = (const float*)d_in[2];
  const float* W2 = (const float*)d_in[3];
  const float* b2 = (const float*)d_in[4];
  const float* W3 = (const float*)d_in[5];
  const float* b3 = (const float*)d_in[6];
  const float* Wr = (const float*)d_in[7];
  const float* br = (const float*)d_in[8];
  float* out = (float*)d_out;

  // ws: [0,4K) flags | 1MB a1buf f16 (32g x 2par x 16x512) |
  //     2MB vpbuf f16 (32g x 2par x 8memb x 16x128)
  unsigned* flags = (unsigned*)d_ws;
  f16* a1buf = (f16*)((char*)d_ws + 4096);
  f16* vpbuf = (f16*)((char*)d_ws + 4096 + (1 << 20));

  hipMemsetAsync(d_ws, 0, 4096, stream);   // reset flags every launch/replay
  node_scan_kernel<<<256, 256, 0, stream>>>(x, W1, b1, W2, b2, W3, b3, Wr, br,
                                            out, flags, a1buf, vpbuf);
}